// Round 13
// baseline (143.660 us; speedup 1.0000x reference)
//
#include <hip/hip_runtime.h>

#define DIM    64
#define NEMB   1024
#define HW     4096      // 64*64
#define NPIX   131072    // 32*64*64
#define NOUT   8388608   // 32*64*64*64
#define PIXBLK 128       // pixels per block
#define NTILE  64        // 1024/16 code tiles
#define TPW    16        // tiles per wave (4 waves cover 64)
#define CAP    512       // worklist capacity (observed ~170 entries/block)
#define MARGIN 2.0f      // >= 5x worst-case screen error (split ~0.2 + f16 ~0.25, x2)

using short8 = __attribute__((ext_vector_type(8))) short;
using f32x4  = __attribute__((ext_vector_type(4))) float;

#define MFMA(A, B, C) __builtin_amdgcn_mfma_f32_16x16x32_bf16((A), (B), (C), 0, 0, 0)

__device__ __forceinline__ unsigned short bf16_rne(float f) {
    unsigned u = __float_as_uint(f);
    return (unsigned short)((u + 0x7fffu + ((u >> 16) & 1u)) >> 16);
}
__device__ __forceinline__ float bf16_val(unsigned short h) {
    return __uint_as_float((unsigned)h << 16);
}
__device__ __forceinline__ void umin64(unsigned long long* p, unsigned long long v) {
    unsigned long long old = *p;
    while (v < old) {
        unsigned long long a = atomicCAS(p, old, v);
        if (a == old) break;
        old = a;
    }
}

// ---------------------------------------------------------------------------
// prep1: cn[j] = ||e_j||^2 (numpy axis-0 order: sequential adds of rounded muls)
// ---------------------------------------------------------------------------
__global__ __launch_bounds__(256) void prep1(const float* __restrict__ embed,
                                             float* __restrict__ cn) {
    const int j = blockIdx.x * 256 + threadIdx.x;
    if (j >= NEMB) return;
    float v = embed[j];
    float s = __fmul_rn(v, v);
#pragma unroll
    for (int d = 1; d < DIM; ++d) {
        v = embed[d * NEMB + j];
        s = __fadd_rn(s, __fmul_rn(v, v));
    }
    cn[j] = s;
}

// ---------------------------------------------------------------------------
// prep2: split -2*embed into bf16 hi/lo in MFMA A-fragment order (== R9-R11,
// verified by absmax=0): flat = ((ct*2+kc)*64 + (g*16+r))*8 + i,
// d = kc*32+g*8+i, code = ct*16+r.
// ---------------------------------------------------------------------------
__global__ __launch_bounds__(256) void prep2(const float* __restrict__ embed,
                                             unsigned short* __restrict__ ehi,
                                             unsigned short* __restrict__ elo) {
    const int gid = blockIdx.x * 256 + threadIdx.x;   // 64*1024 elements
    const int d = gid >> 10;
    const int j = gid & 1023;
    const float es = -2.0f * embed[d * NEMB + j];
    const unsigned short h = bf16_rne(es);
    const unsigned short lo = bf16_rne(es - bf16_val(h));
    const int ct = j >> 4, r = j & 15;
    const int kc = d >> 5, g = (d >> 3) & 3, i = d & 7;
    const int idx = ((ct * 2 + kc) * 64 + (g * 16 + r)) * 8 + i;
    ehi[idx] = h;
    elo[idx] = lo;
}

// ---------------------------------------------------------------------------
// prep3: cn in C-fragment order (== R9-R11): lane l, reg q -> ct*16+(l>>4)*4+q
// ---------------------------------------------------------------------------
__global__ __launch_bounds__(256) void prep3(const float* __restrict__ cn,
                                             float* __restrict__ cnfrag) {
    const int t = blockIdx.x * 256 + threadIdx.x;     // 64*64*4
    const int q = t & 3, l = (t >> 2) & 63, ct = t >> 8;
    cnfrag[t] = cn[ct * 16 + (l >> 4) * 4 + q];
}

// ---------------------------------------------------------------------------
// vq kernel, R12 = R11 + two changes:
//  (1) CAP 768->512: LDS 54272->53248 B crosses the 53.3KB threshold ->
//      3 blocks/CU (12 waves/CU, +50% co-residency). R11 missed it by 939 B.
//  (2) first e-fragment/cn prefetch hoisted ABOVE the stage barrier (depends
//      only on w): loads drain during X staging, screen starts hot.
//  All arithmetic byte-identical to R11 (absmax 0 proven).
// ---------------------------------------------------------------------------
__global__ __launch_bounds__(256)
__attribute__((amdgpu_waves_per_eu(3, 4)))
void vq_kernel(const float* __restrict__ X,
               const float* __restrict__ embed,
               const float* __restrict__ cn,
               const float* __restrict__ cnfrag,
               const unsigned short* __restrict__ ehi,
               const unsigned short* __restrict__ elo,
               float* __restrict__ OUT,
               float* __restrict__ loss) {
    __shared__ float x_lds[DIM][PIXBLK];            // 32 KB
    __shared__ float ff_lds[PIXBLK];                // 512 B
    __shared__ _Float16 tm_lds[NTILE][PIXBLK];      // 16 KB
    __shared__ unsigned long long best_lds[PIXBLK]; // 1 KB
    __shared__ unsigned wl[CAP];                    // 2 KB (aliased as sred later)
    __shared__ int wl_cnt, wl_ovf;

    const int tid  = threadIdx.x;
    const int l    = tid & 63;
    const int w    = tid >> 6;
    const int pix0 = blockIdx.x * PIXBLK;
    const int b    = pix0 >> 12;
    const int p0   = pix0 & 4095;

    // ---- 0. hoisted prefetch of tile ct0 = w*TPW (w-only dependence):
    //      issued before staging; vmcnt drains at the stage barrier, so these
    //      are in-register exactly when the screen loop starts.
    const int ct0 = w * TPW;
    f32x4  cnc = *(const f32x4*)(cnfrag + (ct0 * 64 + l) * 4);
    short8 eh0 = *(const short8*)(ehi + ((ct0 * 2 + 0) * 64 + l) * 8);
    short8 eh1 = *(const short8*)(ehi + ((ct0 * 2 + 1) * 64 + l) * 8);
    short8 el0 = *(const short8*)(elo + ((ct0 * 2 + 0) * 64 + l) * 8);
    short8 el1 = *(const short8*)(elo + ((ct0 * 2 + 1) * 64 + l) * 8);

    // ---- 1. stage with ALL 256 threads: pix = tid&127, d-half = tid>>7
    {
        const int sp = tid & (PIXBLK - 1);
        const int dh = tid >> 7;
        const float* xb = X + (size_t)b * (DIM * HW) + p0 + sp;
#pragma unroll
        for (int k = 0; k < DIM / 2; ++k) {
            const int d = dh * (DIM / 2) + k;
            x_lds[d][sp] = xb[(size_t)d * HW];
        }
        if (tid < PIXBLK) best_lds[tid] = 0xFFFFFFFFFFFFFFFFull;
        if (tid == 0) { wl_cnt = 0; wl_ovf = 0; }
    }
    __syncthreads();

    // ---- 1b. ff from LDS, pairwise-8 (identical op order/values as R0)
    if (tid < PIXBLK) {
        float rr[8];
#pragma unroll
        for (int i = 0; i < 8; ++i) {
            const float v = x_lds[i][tid];
            rr[i] = __fmul_rn(v, v);
        }
#pragma unroll
        for (int i = 8; i < DIM; i += 8)
#pragma unroll
            for (int q = 0; q < 8; ++q) {
                const float v = x_lds[i + q][tid];
                rr[q] = __fadd_rn(rr[q], __fmul_rn(v, v));
            }
        ff_lds[tid] = __fadd_rn(
            __fadd_rn(__fadd_rn(rr[0], rr[1]), __fadd_rn(rr[2], rr[3])),
            __fadd_rn(__fadd_rn(rr[4], rr[5]), __fadd_rn(rr[6], rr[7])));
    }

    // ---- 2. x B-fragments for all 8 subtiles (B[k=d][col=pix]):
    //      lane l holds k=(l>>4)*8+i, col = s*16 + (l&15).
    const int g  = l >> 4;
    const int lr = l & 15;
    short8 xh[8][2];     // 64 VGPR
#pragma unroll
    for (int s = 0; s < 8; ++s)
#pragma unroll
        for (int kc = 0; kc < 2; ++kc)
#pragma unroll
            for (int i = 0; i < 8; ++i) {
                const int d = kc * 32 + g * 8 + i;
                xh[s][kc][i] = (short)bf16_rne(x_lds[d][s * 16 + lr]);
            }

    // ---- 3. screen: wave w owns tiles [16w,16w+16), 1-deep prefetch (==R11)
#pragma unroll 1
    for (int t = 0; t < TPW; ++t) {
        const int ct = ct0 + t;
        f32x4 cnn = cnc;
        short8 eh0n = eh0, eh1n = eh1, el0n = el0, el1n = el1;
        if (t + 1 < TPW) {
            const int c2 = (ct + 1) * 2;
            cnn  = *(const f32x4*)(cnfrag + ((ct + 1) * 64 + l) * 4);
            eh0n = *(const short8*)(ehi + ((c2 + 0) * 64 + l) * 8);
            eh1n = *(const short8*)(ehi + ((c2 + 1) * 64 + l) * 8);
            el0n = *(const short8*)(elo + ((c2 + 0) * 64 + l) * 8);
            el1n = *(const short8*)(elo + ((c2 + 1) * 64 + l) * 8);
        }
#pragma unroll
        for (int s = 0; s < 8; ++s) {
            f32x4 c0 = cnc, c1 = {0.f, 0.f, 0.f, 0.f};
            c0 = MFMA(el0, xh[s][0], c0);
            c1 = MFMA(el1, xh[s][1], c1);
            c0 = MFMA(eh0, xh[s][0], c0);
            c1 = MFMA(eh1, xh[s][1], c1);
            float m = fminf(fminf(c0[0] + c1[0], c0[1] + c1[1]),
                            fminf(c0[2] + c1[2], c0[3] + c1[3]));
            m = fminf(m, __shfl_xor(m, 16, 64));
            m = fminf(m, __shfl_xor(m, 32, 64));
            if (l < 16) tm_lds[ct][s * 16 + l] = (_Float16)m;
        }
        cnc = cnn; eh0 = eh0n; eh1 = eh1n; el0 = el0n; el1 = el1n;
    }
    __syncthreads();

    // ---- 4. enumerate candidate tiles per pixel (4-way min tree)
    if (tid < PIXBLK) {
        float m0 = (float)tm_lds[0][tid], m1 = (float)tm_lds[1][tid];
        float m2 = (float)tm_lds[2][tid], m3 = (float)tm_lds[3][tid];
#pragma unroll
        for (int ct = 4; ct < NTILE; ct += 4) {
            m0 = fminf(m0, (float)tm_lds[ct + 0][tid]);
            m1 = fminf(m1, (float)tm_lds[ct + 1][tid]);
            m2 = fminf(m2, (float)tm_lds[ct + 2][tid]);
            m3 = fminf(m3, (float)tm_lds[ct + 3][tid]);
        }
        const float thr = fminf(fminf(m0, m1), fminf(m2, m3)) + MARGIN;
        for (int ct = 0; ct < NTILE; ++ct)
            if ((float)tm_lds[ct][tid] <= thr) {
                const int slot = atomicAdd(&wl_cnt, 1);
                if (slot < CAP) wl[slot] = (unsigned)((tid << 6) | ct);
                else wl_ovf = 1;
            }
    }
    __syncthreads();

    // ---- 5. cooperative exact rescore: entry -> 16-lane group, lane c = code.
    //      Per-code chain: a = sum_d fmaf(x[d], e[d][j]) sequential-d == R0.
    const int ec  = wl_cnt < CAP ? wl_cnt : CAP;
    const int grp = tid >> 4;      // 16 groups of 16 lanes
    const int cc  = tid & 15;
#pragma unroll 1
    for (int base = 0; base < ec; base += 16) {
        const int e = base + grp;
        unsigned long long pk = 0xFFFFFFFFFFFFFFFFull;
        int pix = 0;
        if (e < ec) {
            const unsigned ent = wl[e];
            pix = (int)(ent >> 6);
            const int j = (int)(ent & 63) * 16 + cc;
            float a = 0.f;
#pragma unroll
            for (int d = 0; d < DIM; ++d)
                a = fmaf(x_lds[d][pix], embed[d * NEMB + j], a);
            const float dist =
                __fadd_rn(__fsub_rn(ff_lds[pix], __fmul_rn(2.f, a)), cn[j]);
            pk = ((unsigned long long)__float_as_uint(dist) << 32) | (unsigned)j;
        }
#pragma unroll
        for (int m = 1; m < 16; m <<= 1) {
            const unsigned long long o = __shfl_xor(pk, m, 64);
            pk = o < pk ? o : pk;
        }
        if (e < ec && cc == 0) umin64(&best_lds[pix], pk);
    }
    __syncthreads();

    if (wl_ovf) {   // safety net: exact scan of all codes (cooperative too)
#pragma unroll 1
        for (int base = 0; base < PIXBLK; base += 16) {
            const int pix = base + grp;
            unsigned long long bb = 0xFFFFFFFFFFFFFFFFull;
#pragma unroll 1
            for (int jq = 0; jq < NEMB / 16; ++jq) {
                const int j = jq * 16 + cc;
                float a = 0.f;
#pragma unroll
                for (int d = 0; d < DIM; ++d)
                    a = fmaf(x_lds[d][pix], embed[d * NEMB + j], a);
                const float dist =
                    __fadd_rn(__fsub_rn(ff_lds[pix], __fmul_rn(2.f, a)), cn[j]);
                const unsigned long long pk =
                    ((unsigned long long)__float_as_uint(dist) << 32) | (unsigned)j;
                bb = pk < bb ? pk : bb;
            }
#pragma unroll
            for (int m = 1; m < 16; m <<= 1) {
                const unsigned long long o = __shfl_xor(bb, m, 64);
                bb = o < bb ? o : bb;
            }
            if (cc == 0) umin64(&best_lds[pix], bb);
        }
        __syncthreads();
    }

    // ---- 6. output + loss (sred aliases wl: disjoint lifetimes)
    float* sred = (float*)wl;
    const int pixe = tid & (PIXBLK - 1);
    const int dh   = tid >> 7;
    const int idx  = (int)(best_lds[pixe] & 0xFFFFFFFFull);
    float lerr = 0.f;
    float* outb = OUT + (size_t)b * (DIM * HW) + p0 + pixe;
#pragma unroll 8
    for (int k = 0; k < DIM / 2; ++k) {
        const int d = dh * (DIM / 2) + k;
        const float qv = embed[d * NEMB + idx];
        const float xv = x_lds[d][pixe];
        const float df = __fsub_rn(qv, xv);
        outb[(size_t)d * HW] = __fadd_rn(xv, df);
        lerr = fmaf(df, df, lerr);
    }

    sred[tid] = lerr;
    __syncthreads();
#pragma unroll
    for (int s = 128; s > 0; s >>= 1) {
        if (tid < s) sred[tid] += sred[tid + s];
        __syncthreads();
    }
    if (tid == 0)
        atomicAdd(loss, sred[0] * (1.0f / (float)NOUT));
}

extern "C" void kernel_launch(void* const* d_in, const int* in_sizes, int n_in,
                              void* d_out, int out_size, void* d_ws, size_t ws_size,
                              hipStream_t stream) {
    const float* X = (const float*)d_in[0];
    const float* E = (const float*)d_in[1];
    float* OUT  = (float*)d_out;
    float* loss = OUT + NOUT;

    // ws layout (bytes): cn 4K | cnfrag 64K | ehi 128K | elo 128K
    char* wsb = (char*)d_ws;
    float* cn            = (float*)(wsb);
    float* cnfrag        = (float*)(wsb + 4096);
    unsigned short* ehi  = (unsigned short*)(wsb + 4096 + 65536);
    unsigned short* elo  = (unsigned short*)(wsb + 4096 + 65536 + 131072);

    hipMemsetAsync(loss, 0, sizeof(float), stream);
    prep1<<<NEMB / 256, 256, 0, stream>>>(E, cn);
    prep2<<<(DIM * NEMB) / 256, 256, 0, stream>>>(E, ehi, elo);
    prep3<<<(NTILE * 64 * 4) / 256, 256, 0, stream>>>(cn, cnfrag);
    vq_kernel<<<NPIX / PIXBLK, 256, 0, stream>>>(X, E, cn, cnfrag, ehi, elo,
                                                 OUT, loss);
}

// Round 14
// 138.740 us; speedup vs baseline: 1.0355x; 1.0355x over previous
//
#include <hip/hip_runtime.h>

#define DIM    64
#define NEMB   1024
#define HW     4096      // 64*64
#define NPIX   131072    // 32*64*64
#define NOUT   8388608   // 32*64*64*64
#define PIXBLK 128       // pixels per block
#define NTILE  64        // 1024/16 code tiles
#define TPW    16        // tiles per wave (4 waves cover 64)
#define CAP    512       // worklist capacity (observed ~170 entries/block)
#define MARGIN 2.0f      // >= 5x worst-case screen error (split ~0.2 + f16 ~0.25, x2)

using short8 = __attribute__((ext_vector_type(8))) short;
using f32x4  = __attribute__((ext_vector_type(4))) float;

#define MFMA(A, B, C) __builtin_amdgcn_mfma_f32_16x16x32_bf16((A), (B), (C), 0, 0, 0)

__device__ __forceinline__ unsigned short bf16_rne(float f) {
    unsigned u = __float_as_uint(f);
    return (unsigned short)((u + 0x7fffu + ((u >> 16) & 1u)) >> 16);
}
__device__ __forceinline__ float bf16_val(unsigned short h) {
    return __uint_as_float((unsigned)h << 16);
}
__device__ __forceinline__ void umin64(unsigned long long* p, unsigned long long v) {
    unsigned long long old = *p;
    while (v < old) {
        unsigned long long a = atomicCAS(p, old, v);
        if (a == old) break;
        old = a;
    }
}

// ---------------------------------------------------------------------------
// prep1: cn[j] = ||e_j||^2 (numpy axis-0 order: sequential adds of rounded muls)
// ---------------------------------------------------------------------------
__global__ __launch_bounds__(256) void prep1(const float* __restrict__ embed,
                                             float* __restrict__ cn) {
    const int j = blockIdx.x * 256 + threadIdx.x;
    if (j >= NEMB) return;
    float v = embed[j];
    float s = __fmul_rn(v, v);
#pragma unroll
    for (int d = 1; d < DIM; ++d) {
        v = embed[d * NEMB + j];
        s = __fadd_rn(s, __fmul_rn(v, v));
    }
    cn[j] = s;
}

// ---------------------------------------------------------------------------
// prep2: split -2*embed into bf16 hi/lo in MFMA A-fragment order (== R9-R12,
// verified by absmax=0): flat = ((ct*2+kc)*64 + (g*16+r))*8 + i,
// d = kc*32+g*8+i, code = ct*16+r.
// ---------------------------------------------------------------------------
__global__ __launch_bounds__(256) void prep2(const float* __restrict__ embed,
                                             unsigned short* __restrict__ ehi,
                                             unsigned short* __restrict__ elo) {
    const int gid = blockIdx.x * 256 + threadIdx.x;   // 64*1024 elements
    const int d = gid >> 10;
    const int j = gid & 1023;
    const float es = -2.0f * embed[d * NEMB + j];
    const unsigned short h = bf16_rne(es);
    const unsigned short lo = bf16_rne(es - bf16_val(h));
    const int ct = j >> 4, r = j & 15;
    const int kc = d >> 5, g = (d >> 3) & 3, i = d & 7;
    const int idx = ((ct * 2 + kc) * 64 + (g * 16 + r)) * 8 + i;
    ehi[idx] = h;
    elo[idx] = lo;
}

// ---------------------------------------------------------------------------
// prep3: cn in C-fragment order (== R9-R12): lane l, reg q -> ct*16+(l>>4)*4+q
// ---------------------------------------------------------------------------
__global__ __launch_bounds__(256) void prep3(const float* __restrict__ cn,
                                             float* __restrict__ cnfrag) {
    const int t = blockIdx.x * 256 + threadIdx.x;     // 64*64*4
    const int q = t & 3, l = (t >> 2) & 63, ct = t >> 8;
    cnfrag[t] = cn[ct * 16 + (l >> 4) * 4 + q];
}

// ---------------------------------------------------------------------------
// vq kernel, R13 = R12 + strip-mined rescore.
//  R12 lesson: occupancy pushes are null; ~80% of cycles are dependency
//  stalls, dominated by the rescore's load->fma serial chain (each embed
//  load ~200cyc L2 feeding the next fmaf; no VGPR headroom to pipeline ->
//  ~13K cyc/entry-batch). Fix: explicit 16-value register strips — 16
//  independent loads issue together, then 16 register fmafs. Latency
//  exposed once per strip (~800 cyc/entry, 15x less). Summation order
//  unchanged (sequential-d fmaf chain) -> bitwise-identical distances.
// ---------------------------------------------------------------------------
__global__ __launch_bounds__(256)
__attribute__((amdgpu_waves_per_eu(3, 4)))
void vq_kernel(const float* __restrict__ X,
               const float* __restrict__ embed,
               const float* __restrict__ cn,
               const float* __restrict__ cnfrag,
               const unsigned short* __restrict__ ehi,
               const unsigned short* __restrict__ elo,
               float* __restrict__ OUT,
               float* __restrict__ loss) {
    __shared__ float x_lds[DIM][PIXBLK];            // 32 KB
    __shared__ float ff_lds[PIXBLK];                // 512 B
    __shared__ _Float16 tm_lds[NTILE][PIXBLK];      // 16 KB
    __shared__ unsigned long long best_lds[PIXBLK]; // 1 KB
    __shared__ unsigned wl[CAP];                    // 2 KB (aliased as sred later)
    __shared__ int wl_cnt, wl_ovf;

    const int tid  = threadIdx.x;
    const int l    = tid & 63;
    const int w    = tid >> 6;
    const int pix0 = blockIdx.x * PIXBLK;
    const int b    = pix0 >> 12;
    const int p0   = pix0 & 4095;

    // ---- 0. hoisted prefetch of tile ct0 = w*TPW (w-only dependence)
    const int ct0 = w * TPW;
    f32x4  cnc = *(const f32x4*)(cnfrag + (ct0 * 64 + l) * 4);
    short8 eh0 = *(const short8*)(ehi + ((ct0 * 2 + 0) * 64 + l) * 8);
    short8 eh1 = *(const short8*)(ehi + ((ct0 * 2 + 1) * 64 + l) * 8);
    short8 el0 = *(const short8*)(elo + ((ct0 * 2 + 0) * 64 + l) * 8);
    short8 el1 = *(const short8*)(elo + ((ct0 * 2 + 1) * 64 + l) * 8);

    // ---- 1. stage with ALL 256 threads: pix = tid&127, d-half = tid>>7
    {
        const int sp = tid & (PIXBLK - 1);
        const int dh = tid >> 7;
        const float* xb = X + (size_t)b * (DIM * HW) + p0 + sp;
#pragma unroll
        for (int k = 0; k < DIM / 2; ++k) {
            const int d = dh * (DIM / 2) + k;
            x_lds[d][sp] = xb[(size_t)d * HW];
        }
        if (tid < PIXBLK) best_lds[tid] = 0xFFFFFFFFFFFFFFFFull;
        if (tid == 0) { wl_cnt = 0; wl_ovf = 0; }
    }
    __syncthreads();

    // ---- 1b. ff from LDS, pairwise-8 (identical op order/values as R0)
    if (tid < PIXBLK) {
        float rr[8];
#pragma unroll
        for (int i = 0; i < 8; ++i) {
            const float v = x_lds[i][tid];
            rr[i] = __fmul_rn(v, v);
        }
#pragma unroll
        for (int i = 8; i < DIM; i += 8)
#pragma unroll
            for (int q = 0; q < 8; ++q) {
                const float v = x_lds[i + q][tid];
                rr[q] = __fadd_rn(rr[q], __fmul_rn(v, v));
            }
        ff_lds[tid] = __fadd_rn(
            __fadd_rn(__fadd_rn(rr[0], rr[1]), __fadd_rn(rr[2], rr[3])),
            __fadd_rn(__fadd_rn(rr[4], rr[5]), __fadd_rn(rr[6], rr[7])));
    }

    // ---- 2. x B-fragments for all 8 subtiles (B[k=d][col=pix]):
    //      lane l holds k=(l>>4)*8+i, col = s*16 + (l&15).
    const int g  = l >> 4;
    const int lr = l & 15;
    short8 xh[8][2];     // 64 VGPR
#pragma unroll
    for (int s = 0; s < 8; ++s)
#pragma unroll
        for (int kc = 0; kc < 2; ++kc)
#pragma unroll
            for (int i = 0; i < 8; ++i) {
                const int d = kc * 32 + g * 8 + i;
                xh[s][kc][i] = (short)bf16_rne(x_lds[d][s * 16 + lr]);
            }

    // ---- 3. screen: wave w owns tiles [16w,16w+16), 1-deep prefetch (==R12)
#pragma unroll 1
    for (int t = 0; t < TPW; ++t) {
        const int ct = ct0 + t;
        f32x4 cnn = cnc;
        short8 eh0n = eh0, eh1n = eh1, el0n = el0, el1n = el1;
        if (t + 1 < TPW) {
            const int c2 = (ct + 1) * 2;
            cnn  = *(const f32x4*)(cnfrag + ((ct + 1) * 64 + l) * 4);
            eh0n = *(const short8*)(ehi + ((c2 + 0) * 64 + l) * 8);
            eh1n = *(const short8*)(ehi + ((c2 + 1) * 64 + l) * 8);
            el0n = *(const short8*)(elo + ((c2 + 0) * 64 + l) * 8);
            el1n = *(const short8*)(elo + ((c2 + 1) * 64 + l) * 8);
        }
#pragma unroll
        for (int s = 0; s < 8; ++s) {
            f32x4 c0 = cnc, c1 = {0.f, 0.f, 0.f, 0.f};
            c0 = MFMA(el0, xh[s][0], c0);
            c1 = MFMA(el1, xh[s][1], c1);
            c0 = MFMA(eh0, xh[s][0], c0);
            c1 = MFMA(eh1, xh[s][1], c1);
            float m = fminf(fminf(c0[0] + c1[0], c0[1] + c1[1]),
                            fminf(c0[2] + c1[2], c0[3] + c1[3]));
            m = fminf(m, __shfl_xor(m, 16, 64));
            m = fminf(m, __shfl_xor(m, 32, 64));
            if (l < 16) tm_lds[ct][s * 16 + l] = (_Float16)m;
        }
        cnc = cnn; eh0 = eh0n; eh1 = eh1n; el0 = el0n; el1 = el1n;
    }
    __syncthreads();

    // ---- 4. enumerate candidate tiles per pixel (4-way min tree)
    if (tid < PIXBLK) {
        float m0 = (float)tm_lds[0][tid], m1 = (float)tm_lds[1][tid];
        float m2 = (float)tm_lds[2][tid], m3 = (float)tm_lds[3][tid];
#pragma unroll
        for (int ct = 4; ct < NTILE; ct += 4) {
            m0 = fminf(m0, (float)tm_lds[ct + 0][tid]);
            m1 = fminf(m1, (float)tm_lds[ct + 1][tid]);
            m2 = fminf(m2, (float)tm_lds[ct + 2][tid]);
            m3 = fminf(m3, (float)tm_lds[ct + 3][tid]);
        }
        const float thr = fminf(fminf(m0, m1), fminf(m2, m3)) + MARGIN;
        for (int ct = 0; ct < NTILE; ++ct)
            if ((float)tm_lds[ct][tid] <= thr) {
                const int slot = atomicAdd(&wl_cnt, 1);
                if (slot < CAP) wl[slot] = (unsigned)((tid << 6) | ct);
                else wl_ovf = 1;
            }
    }
    __syncthreads();

    // ---- 5. cooperative exact rescore, STRIP-MINED: entry -> 16-lane group,
    //      lane c = code. e-loads batched 16 at a time into registers (the
    //      16 loads are independent -> issue together, one latency exposure
    //      per strip); the fmaf chain then runs from registers in the SAME
    //      sequential-d order as R0 (bitwise-identical distance).
    const int ec  = wl_cnt < CAP ? wl_cnt : CAP;
    const int grp = tid >> 4;      // 16 groups of 16 lanes
    const int cc  = tid & 15;
#pragma unroll 1
    for (int base = 0; base < ec; base += 16) {
        const int e = base + grp;
        unsigned long long pk = 0xFFFFFFFFFFFFFFFFull;
        int pix = 0;
        if (e < ec) {
            const unsigned ent = wl[e];
            pix = (int)(ent >> 6);
            const int j = (int)(ent & 63) * 16 + cc;
            float a = 0.f;
#pragma unroll
            for (int dc = 0; dc < 4; ++dc) {
                float ev[16], xv[16];
#pragma unroll
                for (int k = 0; k < 16; ++k)
                    ev[k] = embed[(dc * 16 + k) * NEMB + j];   // 16 indep loads
#pragma unroll
                for (int k = 0; k < 16; ++k)
                    xv[k] = x_lds[dc * 16 + k][pix];           // 16 indep LDS reads
#pragma unroll
                for (int k = 0; k < 16; ++k)
                    a = fmaf(xv[k], ev[k], a);                 // sequential-d == R0
            }
            const float dist =
                __fadd_rn(__fsub_rn(ff_lds[pix], __fmul_rn(2.f, a)), cn[j]);
            pk = ((unsigned long long)__float_as_uint(dist) << 32) | (unsigned)j;
        }
#pragma unroll
        for (int m = 1; m < 16; m <<= 1) {
            const unsigned long long o = __shfl_xor(pk, m, 64);
            pk = o < pk ? o : pk;
        }
        if (e < ec && cc == 0) umin64(&best_lds[pix], pk);
    }
    __syncthreads();

    if (wl_ovf) {   // safety net: exact scan of all codes (strip-mined too)
#pragma unroll 1
        for (int base = 0; base < PIXBLK; base += 16) {
            const int pix = base + grp;
            unsigned long long bb = 0xFFFFFFFFFFFFFFFFull;
#pragma unroll 1
            for (int jq = 0; jq < NEMB / 16; ++jq) {
                const int j = jq * 16 + cc;
                float a = 0.f;
#pragma unroll
                for (int dc = 0; dc < 4; ++dc) {
                    float ev[16], xv[16];
#pragma unroll
                    for (int k = 0; k < 16; ++k)
                        ev[k] = embed[(dc * 16 + k) * NEMB + j];
#pragma unroll
                    for (int k = 0; k < 16; ++k)
                        xv[k] = x_lds[dc * 16 + k][pix];
#pragma unroll
                    for (int k = 0; k < 16; ++k)
                        a = fmaf(xv[k], ev[k], a);
                }
                const float dist =
                    __fadd_rn(__fsub_rn(ff_lds[pix], __fmul_rn(2.f, a)), cn[j]);
                const unsigned long long pk =
                    ((unsigned long long)__float_as_uint(dist) << 32) | (unsigned)j;
                bb = pk < bb ? pk : bb;
            }
#pragma unroll
            for (int m = 1; m < 16; m <<= 1) {
                const unsigned long long o = __shfl_xor(bb, m, 64);
                bb = o < bb ? o : bb;
            }
            if (cc == 0) umin64(&best_lds[pix], bb);
        }
        __syncthreads();
    }

    // ---- 6. output + loss (sred aliases wl: disjoint lifetimes)
    float* sred = (float*)wl;
    const int pixe = tid & (PIXBLK - 1);
    const int dh   = tid >> 7;
    const int idx  = (int)(best_lds[pixe] & 0xFFFFFFFFull);
    float lerr = 0.f;
    float* outb = OUT + (size_t)b * (DIM * HW) + p0 + pixe;
#pragma unroll 8
    for (int k = 0; k < DIM / 2; ++k) {
        const int d = dh * (DIM / 2) + k;
        const float qv = embed[d * NEMB + idx];
        const float xv = x_lds[d][pixe];
        const float df = __fsub_rn(qv, xv);
        outb[(size_t)d * HW] = __fadd_rn(xv, df);
        lerr = fmaf(df, df, lerr);
    }

    sred[tid] = lerr;
    __syncthreads();
#pragma unroll
    for (int s = 128; s > 0; s >>= 1) {
        if (tid < s) sred[tid] += sred[tid + s];
        __syncthreads();
    }
    if (tid == 0)
        atomicAdd(loss, sred[0] * (1.0f / (float)NOUT));
}

extern "C" void kernel_launch(void* const* d_in, const int* in_sizes, int n_in,
                              void* d_out, int out_size, void* d_ws, size_t ws_size,
                              hipStream_t stream) {
    const float* X = (const float*)d_in[0];
    const float* E = (const float*)d_in[1];
    float* OUT  = (float*)d_out;
    float* loss = OUT + NOUT;

    // ws layout (bytes): cn 4K | cnfrag 64K | ehi 128K | elo 128K
    char* wsb = (char*)d_ws;
    float* cn            = (float*)(wsb);
    float* cnfrag        = (float*)(wsb + 4096);
    unsigned short* ehi  = (unsigned short*)(wsb + 4096 + 65536);
    unsigned short* elo  = (unsigned short*)(wsb + 4096 + 65536 + 131072);

    hipMemsetAsync(loss, 0, sizeof(float), stream);
    prep1<<<NEMB / 256, 256, 0, stream>>>(E, cn);
    prep2<<<(DIM * NEMB) / 256, 256, 0, stream>>>(E, ehi, elo);
    prep3<<<(NTILE * 64 * 4) / 256, 256, 0, stream>>>(cn, cnfrag);
    vq_kernel<<<NPIX / PIXBLK, 256, 0, stream>>>(X, E, cn, cnfrag, ehi, elo,
                                                 OUT, loss);
}